// Round 1
// baseline (21.874 us; speedup 1.0000x reference)
//
#include <hip/hip_runtime.h>

#define SEQ 512
#define DIM 1024
#define HD  512
#define NSPAN 4068   // 505*8 + 28
#define NFULL 4040   // rows 0..504 * 8

// Kernel 1: per-token dot products against W for start/end halves.
// One wave (64 lanes) per (b, s) row; 4 rows per 256-thread block.
__global__ __launch_bounds__(256) void dot_kernel(
    const float* __restrict__ emb,   // [B*S, 1024]
    const float* __restrict__ W,     // [512]
    float* __restrict__ sdot,        // [B*S]
    float* __restrict__ edot)        // [B*S]
{
    __shared__ float w[HD];
    const int tid = threadIdx.x;
    w[tid]       = W[tid];
    w[tid + 256] = W[tid + 256];
    __syncthreads();

    const int wave = tid >> 6;
    const int lane = tid & 63;
    const int row  = blockIdx.x * 4 + wave;          // 16384 rows total
    const float* p = emb + (size_t)row * DIM;

    float s = 0.f, e = 0.f;
#pragma unroll
    for (int c = 0; c < 2; ++c) {
        const int d = c * 256 + lane * 4;            // 0..508, coalesced float4
        const float4 v = *reinterpret_cast<const float4*>(p + d);
        s += v.x * w[d] + v.y * w[d + 1] + v.z * w[d + 2] + v.w * w[d + 3];
        const float4 u = *reinterpret_cast<const float4*>(p + HD + d);
        e += u.x * w[d] + u.y * w[d + 1] + u.z * w[d + 2] + u.w * w[d + 3];
    }
#pragma unroll
    for (int off = 32; off >= 1; off >>= 1) {
        s += __shfl_xor(s, off, 64);
        e += __shfl_xor(e, off, 64);
    }
    if (lane == 0) { sdot[row] = s; edot[row] = e; }
}

// Kernel 2: per-batch masked softmax over the 4068 banded spans.
__global__ __launch_bounds__(256) void softmax_kernel(
    const float* __restrict__ sdot,   // [B, S]
    const float* __restrict__ edot,   // [B, S]
    const int*   __restrict__ ttid,   // [B, S]
    const int*   __restrict__ amask,  // [B, S]
    const float* __restrict__ biasp,  // [1]
    float* __restrict__ out)          // [B, NSPAN]
{
    const int b   = blockIdx.x;
    const int tid = threadIdx.x;

    __shared__ float sd[SEQ], ed[SEQ], mk[SEQ];
    __shared__ float logits[NSPAN];
    __shared__ float red[8];

    const float bias = biasp[0];
    for (int i = tid; i < SEQ; i += 256) {
        sd[i] = sdot[b * SEQ + i];
        ed[i] = edot[b * SEQ + i];
        mk[i] = (float)(ttid[b * SEQ + i] * amask[b * SEQ + i]);
    }
    __syncthreads();

    float lmax = -3.0e38f;
    for (int n = tid; n < NSPAN; n += 256) {
        int si, ei;
        if (n < NFULL) {
            si = n >> 3;
            ei = si + (n & 7);
        } else {                      // 28-entry tail: rows 505..511
            int m = n - NFULL;
            int t = 0, cnt = 7, off = 0;
            while (m >= off + cnt) { off += cnt; --cnt; ++t; }
            si = 505 + t;
            ei = si + (m - off);
        }
        float lg = sd[si] + ed[ei] + bias;
        lg -= 1.0e7f * (1.0f - mk[si] * mk[ei]);   // matches reference masking
        logits[n] = lg;
        lmax = fmaxf(lmax, lg);
    }

    // block max: 64-lane butterfly then across 4 waves via LDS
#pragma unroll
    for (int off = 32; off >= 1; off >>= 1)
        lmax = fmaxf(lmax, __shfl_xor(lmax, off, 64));
    if ((tid & 63) == 0) red[tid >> 6] = lmax;
    __syncthreads();
    const float gmax = fmaxf(fmaxf(red[0], red[1]), fmaxf(red[2], red[3]));

    float lsum = 0.f;
    for (int n = tid; n < NSPAN; n += 256)
        lsum += __expf(logits[n] - gmax);
#pragma unroll
    for (int off = 32; off >= 1; off >>= 1)
        lsum += __shfl_xor(lsum, off, 64);
    if ((tid & 63) == 0) red[4 + (tid >> 6)] = lsum;
    __syncthreads();
    const float inv = 1.0f / (red[4] + red[5] + red[6] + red[7]);

    for (int n = tid; n < NSPAN; n += 256)
        out[(size_t)b * NSPAN + n] = __expf(logits[n] - gmax) * inv;
}

extern "C" void kernel_launch(void* const* d_in, const int* in_sizes, int n_in,
                              void* d_out, int out_size, void* d_ws, size_t ws_size,
                              hipStream_t stream) {
    const float* emb   = (const float*)d_in[0];  // [32,512,1024] f32
    const int*   ttid  = (const int*)d_in[1];    // [32,512]
    const int*   amask = (const int*)d_in[2];    // [32,512]
    const float* W     = (const float*)d_in[3];  // [512,1]
    const float* biasp = (const float*)d_in[4];  // [1]
    float*       out   = (float*)d_out;          // [32,4068]

    float* sdot = (float*)d_ws;                  // 16384 floats
    float* edot = sdot + 32 * SEQ;               // 16384 floats

    dot_kernel<<<dim3(32 * SEQ / 4), dim3(256), 0, stream>>>(emb, W, sdot, edot);
    softmax_kernel<<<dim3(32), dim3(256), 0, stream>>>(sdot, edot, ttid, amask, biasp, out);
}

// Round 2
// 20.114 us; speedup vs baseline: 1.0875x; 1.0875x over previous
//
#include <hip/hip_runtime.h>

#define SEQ 512
#define DIM 1024
#define HD  512
#define NSPAN 4068   // 505*8 + 28
#define NFULL 4040   // rows 0..504 * 8
#define ROWS_PER_WAVE 4

// Kernel 1: per-token dot products against W for start/end halves.
// One wave per 4 rows; W held in registers (each lane only needs 8 fixed
// elements of W). No LDS, no syncthreads.
__global__ __launch_bounds__(256) void dot_kernel(
    const float* __restrict__ emb,   // [B*S, 1024]
    const float* __restrict__ W,     // [512]
    float* __restrict__ sdot,        // [B*S]
    float* __restrict__ edot)        // [B*S]
{
    const int tid  = threadIdx.x;
    const int wave = tid >> 6;
    const int lane = tid & 63;
    const int d0   = lane * 4;                        // 0..252

    const float4 w0 = *reinterpret_cast<const float4*>(W + d0);        // L1/L2 hot
    const float4 w1 = *reinterpret_cast<const float4*>(W + 256 + d0);

    const int row0 = (blockIdx.x * 4 + wave) * ROWS_PER_WAVE;

#pragma unroll
    for (int r = 0; r < ROWS_PER_WAVE; ++r) {
        const int row  = row0 + r;
        const float* p = emb + (size_t)row * DIM;

        const float4 v0 = *reinterpret_cast<const float4*>(p + d0);
        const float4 v1 = *reinterpret_cast<const float4*>(p + 256 + d0);
        const float4 u0 = *reinterpret_cast<const float4*>(p + HD + d0);
        const float4 u1 = *reinterpret_cast<const float4*>(p + HD + 256 + d0);

        float s = v0.x * w0.x + v0.y * w0.y + v0.z * w0.z + v0.w * w0.w
                + v1.x * w1.x + v1.y * w1.y + v1.z * w1.z + v1.w * w1.w;
        float e = u0.x * w0.x + u0.y * w0.y + u0.z * w0.z + u0.w * w0.w
                + u1.x * w1.x + u1.y * w1.y + u1.z * w1.z + u1.w * w1.w;

#pragma unroll
        for (int off = 32; off >= 1; off >>= 1) {
            s += __shfl_xor(s, off, 64);
            e += __shfl_xor(e, off, 64);
        }
        if (lane == 0) { sdot[row] = s; edot[row] = e; }
    }
}

// Kernel 2: per-batch masked softmax over the 4068 banded spans.
__global__ __launch_bounds__(512) void softmax_kernel(
    const float* __restrict__ sdot,   // [B, S]
    const float* __restrict__ edot,   // [B, S]
    const int*   __restrict__ ttid,   // [B, S]
    const int*   __restrict__ amask,  // [B, S]
    const float* __restrict__ biasp,  // [1]
    float* __restrict__ out)          // [B, NSPAN]
{
    const int b   = blockIdx.x;
    const int tid = threadIdx.x;

    __shared__ float sd[SEQ], ed[SEQ], mk[SEQ];
    __shared__ float logits[NSPAN];
    __shared__ float red[16];

    const float bias = biasp[0];
    if (tid < SEQ) {
        sd[tid] = sdot[b * SEQ + tid];
        ed[tid] = edot[b * SEQ + tid];
        mk[tid] = (float)(ttid[b * SEQ + tid] * amask[b * SEQ + tid]);
    }
    __syncthreads();

    float lmax = -3.0e38f;
    for (int n = tid; n < NSPAN; n += 512) {
        int si, ei;
        if (n < NFULL) {
            si = n >> 3;
            ei = si + (n & 7);
        } else {                      // 28-entry tail: rows 505..511
            int m = n - NFULL;
            int t = 0, cnt = 7, off = 0;
            while (m >= off + cnt) { off += cnt; --cnt; ++t; }
            si = 505 + t;
            ei = si + (m - off);
        }
        float lg = sd[si] + ed[ei] + bias;
        lg -= 1.0e7f * (1.0f - mk[si] * mk[ei]);   // matches reference masking
        logits[n] = lg;
        lmax = fmaxf(lmax, lg);
    }

#pragma unroll
    for (int off = 32; off >= 1; off >>= 1)
        lmax = fmaxf(lmax, __shfl_xor(lmax, off, 64));
    if ((tid & 63) == 0) red[tid >> 6] = lmax;
    __syncthreads();
    float gmax = red[0];
#pragma unroll
    for (int i = 1; i < 8; ++i) gmax = fmaxf(gmax, red[i]);

    float lsum = 0.f;
    for (int n = tid; n < NSPAN; n += 512) {
        const float pz = __expf(logits[n] - gmax);
        logits[n] = pz;               // cache exp, single expf per span
        lsum += pz;
    }
#pragma unroll
    for (int off = 32; off >= 1; off >>= 1)
        lsum += __shfl_xor(lsum, off, 64);
    if ((tid & 63) == 0) red[8 + (tid >> 6)] = lsum;
    __syncthreads();
    float tot = red[8];
#pragma unroll
    for (int i = 9; i < 16; ++i) tot += red[i];
    const float inv = 1.0f / tot;

    for (int n = tid; n < NSPAN; n += 512)
        out[(size_t)b * NSPAN + n] = logits[n] * inv;
}

extern "C" void kernel_launch(void* const* d_in, const int* in_sizes, int n_in,
                              void* d_out, int out_size, void* d_ws, size_t ws_size,
                              hipStream_t stream) {
    const float* emb   = (const float*)d_in[0];  // [32,512,1024] f32
    const int*   ttid  = (const int*)d_in[1];    // [32,512]
    const int*   amask = (const int*)d_in[2];    // [32,512]
    const float* W     = (const float*)d_in[3];  // [512,1]
    const float* biasp = (const float*)d_in[4];  // [1]
    float*       out   = (float*)d_out;          // [32,4068]

    float* sdot = (float*)d_ws;                  // 16384 floats
    float* edot = sdot + 32 * SEQ;               // 16384 floats

    // 16384 rows / (4 waves * 4 rows per wave) = 1024 blocks
    dot_kernel<<<dim3(1024), dim3(256), 0, stream>>>(emb, W, sdot, edot);
    softmax_kernel<<<dim3(32), dim3(512), 0, stream>>>(sdot, edot, ttid, amask, biasp, out);
}